// Round 8
// baseline (437.775 us; speedup 1.0000x reference)
//
#include <hip/hip_runtime.h>
#include <stdint.h>

#define B_ 4
#define S_ 2048
#define D_ 256
#define NH_ 12
#define M_ (B_*S_)      // 8192 rows of flattened input
#define J_ (NH_*D_)     // 3072 projection cols
#define LOG2E_ 1.4426950408889634f

typedef __bf16 bf16;
typedef __bf16 bf16x8 __attribute__((ext_vector_type(8)));
typedef __bf16 bf16x4 __attribute__((ext_vector_type(4)));
typedef float  f32x4  __attribute__((ext_vector_type(4)));

#define MFMA16(a,b,c) __builtin_amdgcn_mfma_f32_16x16x32_bf16(a,b,c,0,0,0)

__device__ __forceinline__ void g2lds16(void* l, const void* g) {
  __builtin_amdgcn_global_load_lds(
      (const __attribute__((address_space(1))) unsigned int*)g,
      (__attribute__((address_space(3))) unsigned int*)l, 16, 0, 0);
}

// ---------- prep: X fp32->bf16 (blocks 0..2047) + weight transpose (2048..2431) ----------
__global__ __launch_bounds__(256) void prep_k(const float* __restrict__ X,
                                              bf16* __restrict__ Xbf,
                                              const float* __restrict__ Wqk,
                                              bf16* __restrict__ Wqkt,
                                              const float* __restrict__ Wv,
                                              bf16* __restrict__ Wvt) {
  int bid = blockIdx.x;
  if (bid < 2048) {
    int i = bid * 256 + threadIdx.x;
    f32x4 v = *(const f32x4*)(X + (size_t)i * 4);
    bf16x4 o;
#pragma unroll
    for (int k = 0; k < 4; ++k) o[k] = (bf16)v[k];
    *(bf16x4*)(Xbf + (size_t)i * 4) = o;
  } else {
    int q = bid - 2048;                        // 0..383 = z*192 + y*12 + x
    const float* W = (q >= 192) ? Wv : Wqk;
    bf16* Wt       = (q >= 192) ? Wvt : Wqkt;
    q %= 192;
    int c0 = (q / 12) * 16;
    int j  = (q % 12) * 256 + threadIdx.x;     // coalesced over j
    bf16x8 v0, v1;
#pragma unroll
    for (int i = 0; i < 8; ++i) v0[i] = (bf16)W[(size_t)(c0 + i) * J_ + j];
#pragma unroll
    for (int i = 0; i < 8; ++i) v1[i] = (bf16)W[(size_t)(c0 + 8 + i) * J_ + j];
    *(bf16x8*)(Wt + (size_t)j * D_ + c0)     = v0;
    *(bf16x8*)(Wt + (size_t)j * D_ + c0 + 8) = v1;
  }
}

// ---------------- mask tile flags body: 1 if 64x64 tile is all ones ----------------
__device__ __forceinline__ void mask_flags_body(const int* __restrict__ mask,
                                                int* __restrict__ flags, int bx) {
  int ft = bx & 31, st = (bx >> 5) & 31, b = bx >> 10;
  int t = threadIdx.x;
  const int4* mp4 = (const int4*)(mask + (size_t)b * S_ * S_ +
                                  (size_t)(st * 64 + (t >> 2)) * S_ + ft * 64 + (t & 3) * 16);
  bool ok = true;
#pragma unroll
  for (int i = 0; i < 4; ++i) {
    int4 v = mp4[i];
    ok &= (v.x == 1) & (v.y == 1) & (v.z == 1) & (v.w == 1);
  }
  __shared__ int flag;
  if (t == 0) flag = 1;
  __syncthreads();
  if (!ok) flag = 0;                   // benign race, all write 0
  __syncthreads();
  if (t == 0) flags[bx] = flag;
}

// ---------------- GEMM body: C[M][N] = (A[M][256] * Bm[N][256]^T + bias)*scale --------
// 128x128 tile, BK=64, 4 waves each 64x64. XOR 8-chunk swizzle -> 2-way banks.
// R15: double-buffered LDS + 1-iter prefetch (454->417us total with setprio).
// R18: scale param — QK proj epilogue folds log2e so attn uses bare v_exp_f32.
__device__ __forceinline__ void gemm_body(
    const bf16* __restrict__ A, const bf16* __restrict__ Bm,
    const float* __restrict__ bias, bf16* __restrict__ C,
    int Ndim, int bias_mode, float scale, int bid)
{
  __shared__ bf16 As[2][128 * 64];
  __shared__ bf16 Bs[2][128 * 64];
  const int nbn = Ndim >> 7;
  const int bm = bid / nbn, bn = bid % nbn;
  const int t = threadIdx.x, w = t >> 6, l = t & 63;
  const int lane16 = l & 15, quad = l >> 4;
  const int wm = (w & 1) << 6, wn = (w >> 1) << 6;
  const int srow = t >> 3;
  const int gc = (t & 7) ^ (srow & 7);
  const bf16* Ag = A + (size_t)((bm << 7) + srow) * 256 + gc * 8;
  const bf16* Bg = Bm + (size_t)((bn << 7) + srow) * 256 + gc * 8;

  auto stage = [&](int buf, int k0) {
#pragma unroll
    for (int i = 0; i < 4; ++i)
      g2lds16(&As[buf][(size_t)(i * 256 + (w << 6)) * 8], Ag + (size_t)i * 32 * 256 + k0);
#pragma unroll
    for (int i = 0; i < 4; ++i)
      g2lds16(&Bs[buf][(size_t)(i * 256 + (w << 6)) * 8], Bg + (size_t)i * 32 * 256 + k0);
  };

  f32x4 acc[4][4] = {};
  stage(0, 0);                          // prologue prefetch
  int cur = 0;
  for (int k0 = 0; k0 < 256; k0 += 64) {
    __syncthreads();                    // drains DMA(cur) issued one iter ago
    if (k0 + 64 < 256) stage(cur ^ 1, k0 + 64);  // prefetch under compute
#pragma unroll
    for (int kt = 0; kt < 2; ++kt) {
      bf16x8 af[4], bfr[4];
#pragma unroll
      for (int i = 0; i < 4; ++i)
        af[i] = *(const bf16x8*)(&As[cur][(wm + i * 16 + lane16) * 64 +
                                 (((kt * 4 + quad) ^ (lane16 & 7)) * 8)]);
#pragma unroll
      for (int i = 0; i < 4; ++i)
        bfr[i] = *(const bf16x8*)(&Bs[cur][(wn + i * 16 + lane16) * 64 +
                                  (((kt * 4 + quad) ^ (lane16 & 7)) * 8)]);
#pragma unroll
      for (int i = 0; i < 4; ++i)
#pragma unroll
        for (int jx = 0; jx < 4; ++jx)
          acc[i][jx] = MFMA16(af[i], bfr[jx], acc[i][jx]);
    }
    cur ^= 1;
  }
#pragma unroll
  for (int i = 0; i < 4; ++i)
#pragma unroll
    for (int jx = 0; jx < 4; ++jx) {
      int col = (bn << 7) + wn + jx * 16 + lane16;
#pragma unroll
      for (int r = 0; r < 4; ++r) {
        int row = (bm << 7) + wm + i * 16 + quad * 4 + r;
        float v = (acc[i][jx][r] + (bias_mode ? bias[row] : bias[col])) * scale;
        C[(size_t)row * Ndim + col] = (bf16)v;
      }
    }
}

// R17: both projections + mask_flags in ONE dispatch. blocks [0,1536) QK proj,
// [1536,3072) V^T proj, [3072,7168) mask flags (memory-bound tail, hides).
__global__ __launch_bounds__(256) void gemm_flags(
    const bf16* __restrict__ Xbf, const bf16* __restrict__ Wqkt,
    const float* __restrict__ bqk, bf16* __restrict__ QKw,
    const bf16* __restrict__ Wvt, const float* __restrict__ bv,
    bf16* __restrict__ Vtw,
    const int* __restrict__ mask, int* __restrict__ flags)
{
  int bid = blockIdx.x;
  if (bid < 1536)      gemm_body(Xbf, Wqkt, bqk, QKw, J_, 0, LOG2E_, bid);
  else if (bid < 3072) gemm_body(Wvt, Xbf, bv, Vtw, M_, 1, 1.0f, bid - 1536);
  else                 mask_flags_body(mask, flags, bid - 3072);
}

// ---------------- fused attention ----------------
// XCD-swizzled grid. Block: 4 waves, 128 s-rows; wave owns 32 s-rows for QK.
// TRANSPOSED QK (A=K-frag, B=Q-frag) -> St C-layout col=lane16=s, row=quad*4+r=f.
// K/V double-buffered in LDS, 1-iter prefetch.
// REGISTER CLIFF (R6/R7 lesson): 128 VGPR + 128 AGPR (oacc) = 256/wave =
// EXACTLY 2 waves/SIMD. Any +live-VGPR (e.g. cross-iter sfr pipeline: +16)
// -> 1 wave/SIMD catastrophe. V STAYS IN LDS (R6: global-V scatter 256->385).
// NEVER raise launch_bounds min-waves above 2 (r9). NEVER persistent (r12).
// R13 no atomics (331->286). R14 f-split (286->275). R15 setprio (->258).
// R16 PV d-split + raw lgkm mid-barrier (->256). R17 revert V-evict.
// R18: QKw pre-scaled by log2e -> exp2f (saves 16 v_mul/lane/iter); mask
// constant scaled; vfr reads hoisted above the lgkm barrier (their latency
// overlaps the barrier wait; Vs[cur] is valid since the top sync).
template<int HS>
__global__ __launch_bounds__(256, 2) void attn_k(
    const bf16* __restrict__ X, const bf16* __restrict__ QK, const bf16* __restrict__ Vt,
    const int* __restrict__ mask, const int* __restrict__ flags,
    bf16* __restrict__ Part, float* __restrict__ Lsum)
{
  __shared__ bf16 Ks[2][32 * 256];
  __shared__ bf16 Vs[2][256 * 32];
  __shared__ bf16 Ps[4][32 * 40];
  // XCD-aware remap: i = xcd + 8*round; round = gh_sub*16 + st; gh = xcd + 8*gh_sub
  const int i  = blockIdx.x;
  const int x  = i & 7, rr = i >> 3;
  const int gh = x + 8 * (rr >> 4);            // HS: 0..95 = half*48 + g ; else 0..47
  const int st = rr & 15;                      // 128-row s-tile
  const int h  = HS ? (gh >= 48 ? 1 : 0) : 0;
  const int g  = gh - 48 * h;                  // 0..47 = b*12+n
  const int b  = g / 12, n = g % 12;
  const int f_beg = h * 1024;
  const int f_end = f_beg + (HS ? 1024 : 2048);
  const int t = threadIdx.x, w = t >> 6, l = t & 63;
  const int lane16 = l & 15, quad = l >> 4;
  const int sw = (st << 7) + (w << 5);          // wave's first of 32 s-rows (QK phase)
  const bf16* Xb = X + (size_t)b * S_ * D_;
  bf16x8 qf[2][8];                              // Q frags (B operand): 2 s-tiles x 256 k
#pragma unroll
  for (int ts = 0; ts < 2; ++ts)
#pragma unroll
    for (int kt = 0; kt < 8; ++kt)
      qf[ts][kt] = *(const bf16x8*)(Xb + (size_t)(sw + ts * 16 + lane16) * D_ + kt * 32 + quad * 8);
  const bf16* QKb = QK + (size_t)b * S_ * J_ + n * D_;
  const bf16* Vtb = Vt + (size_t)n * D_ * M_ + (size_t)b * S_;
  // flags row for this wave's 64-row tile: st*2 + (w>>1); f-index is absolute
  const int* flagb = flags + (b * 32 + st * 2 + (w >> 1)) * 32;
  f32x4 oacc[8][4] = {};                        // O[128s][64d]: [stile][dtile], d-split
  float lsum[2] = {0.f, 0.f};                   // per-lane partial row sums (s=lane16)

  // staging helper: loads f-tile f0 into buffer `buf`
  auto stage = [&](int buf, int f0) {
#pragma unroll
    for (int ii = 0; ii < 4; ++ii) {
      int frow = ii * 8 + (t >> 5);
      int dc = (t & 31) ^ (frow & 7);
      g2lds16(&Ks[buf][ii * 2048 + (w << 9)], QKb + (size_t)(f0 + frow) * J_ + dc * 8);
    }
#pragma unroll
    for (int ii = 0; ii < 4; ++ii) {
      int drow = ii * 64 + (t >> 2);
      int fc = (t & 3) ^ ((drow >> 1) & 3);
      g2lds16(&Vs[buf][ii * 2048 + (w << 9)], Vtb + (size_t)drow * M_ + f0 + fc * 8);
    }
  };

  stage(0, f_beg);                              // prologue prefetch
  int cur = 0;
  for (int f0 = f_beg; f0 < f_end; f0 += 32) {
    __syncthreads();       // drains DMA(cur) (issued a full iter ago); buf cur^1 free
    if (f0 + 32 < f_end) stage(cur ^ 1, f0 + 32);  // prefetch next tile under compute
    // St = K Q^T : C-layout col=lane16=s, row=quad*4+r=f.  A=kf, B=qf.
    f32x4 sfr[2][2] = {};                       // [ts][ct]
    __builtin_amdgcn_s_setprio(1);
#pragma unroll
    for (int kt = 0; kt < 8; ++kt)
#pragma unroll
      for (int ct = 0; ct < 2; ++ct) {
        int fl = ct * 16 + lane16;              // A m-index rows f
        bf16x8 kf = *(const bf16x8*)(&Ks[cur][fl * 256 + (((kt * 4 + quad) ^ (fl & 7)) * 8)]);
        sfr[0][ct] = MFMA16(kf, qf[0][kt], sfr[0][ct]);
        sfr[1][ct] = MFMA16(kf, qf[1][kt], sfr[1][ct]);
      }
    __builtin_amdgcn_s_setprio(0);
    // sfr is pre-scaled by log2e (GEMM epilogue) -> bare exp2
    float ex[2][2][4];
    if (flagb[f0 >> 6]) {
#pragma unroll
      for (int ts = 0; ts < 2; ++ts)
#pragma unroll
        for (int ct = 0; ct < 2; ++ct)
#pragma unroll
          for (int r = 0; r < 4; ++r) ex[ts][ct][r] = exp2f(sfr[ts][ct][r]);
    } else {
#pragma unroll
      for (int ts = 0; ts < 2; ++ts)
#pragma unroll
        for (int ct = 0; ct < 2; ++ct)
#pragma unroll
          for (int r = 0; r < 4; ++r) {
            int s = sw + ts * 16 + lane16, f = f0 + ct * 16 + quad * 4 + r;
            float add = (1.0f - (float)mask[(size_t)b * S_ * S_ + (size_t)s * S_ + f])
                        * (-10000.0f * LOG2E_);
            ex[ts][ct][r] = exp2f(sfr[ts][ct][r] + add);
          }
    }
#pragma unroll
    for (int ts = 0; ts < 2; ++ts)
      lsum[ts] += ex[ts][0][0] + ex[ts][0][1] + ex[ts][0][2] + ex[ts][0][3]
                + ex[ts][1][0] + ex[ts][1][1] + ex[ts][1][2] + ex[ts][1][3];
    // P -> LDS in A-operand orientation [s=row][f=col], 4 ds_write_b64 per wave
#pragma unroll
    for (int ts = 0; ts < 2; ++ts)
#pragma unroll
      for (int ct = 0; ct < 2; ++ct) {
        int base = (ts * 16 + lane16) * 40 + ct * 16 + quad * 4;
        bf16x4 pv;
        pv[0] = (bf16)ex[ts][ct][0]; pv[1] = (bf16)ex[ts][ct][1];
        pv[2] = (bf16)ex[ts][ct][2]; pv[3] = (bf16)ex[ts][ct][3];
        *(bf16x4*)(&Ps[w][base]) = pv;
      }
    // vfr reads issued BEFORE the barrier: Vs[cur] is valid since top sync;
    // lgkmcnt(0) covers them, so their latency overlaps the barrier wait.
    bf16x8 vfr[4];
#pragma unroll
    for (int dtile = 0; dtile < 4; ++dtile) {
      int dl = (w << 6) + dtile * 16 + lane16;
      vfr[dtile] = *(const bf16x8*)(&Vs[cur][dl * 32 + ((quad ^ ((dl >> 1) & 3)) * 8)]);
    }
    // Ps is BLOCK-shared: publish writes + barrier, but do NOT drain vmcnt —
    // the K/V prefetch DMA must stay in flight.
    asm volatile("s_waitcnt lgkmcnt(0)\n\ts_barrier" ::: "memory");
    // PV d-split: wave owns d in [64w, 64w+64) for ALL 128 block s-rows.
    __builtin_amdgcn_s_setprio(1);
#pragma unroll
    for (int stile = 0; stile < 8; ++stile) {
      bf16x8 pfr = *(const bf16x8*)(&Ps[stile >> 1][(((stile & 1) << 4) + lane16) * 40 + quad * 8]);
#pragma unroll
      for (int dtile = 0; dtile < 4; ++dtile)
        oacc[stile][dtile] = MFMA16(pfr, vfr[dtile], oacc[stile][dtile]);
    }
    __builtin_amdgcn_s_setprio(0);
    cur ^= 1;
  }
  // finalize row sums: reduce across quads (lanes s, s+16, s+32, s+48)
  float tot[2];
#pragma unroll
  for (int ts = 0; ts < 2; ++ts) {
    float rs = lsum[ts];
    rs += __shfl_xor(rs, 16);
    rs += __shfl_xor(rs, 32);
    tot[ts] = rs;                               // every lane: total for s=ts*16+lane16
  }
  // write UN-normalized partial context (bf16) + row sums — exclusive writer
  bf16*  Cb = Part + (size_t)(h * 48 + g) * S_ * D_;
  float* Lb = Lsum + (size_t)(h * 48 + g) * S_;
  if (l < 16) {                                 // quad==0 lanes hold s = ts*16 + l
#pragma unroll
    for (int ts = 0; ts < 2; ++ts) Lb[sw + ts * 16 + l] = tot[ts];
  }
  // O epilogue (d-split layout): s = st*128 + stile*16 + quad*4 + r,
  // d = w*64 + dtile*16 + lane16
#pragma unroll
  for (int stile = 0; stile < 8; ++stile)
#pragma unroll
    for (int r = 0; r < 4; ++r) {
      int s = (st << 7) + stile * 16 + quad * 4 + r;
#pragma unroll
      for (int dtile = 0; dtile < 4; ++dtile) {
        int d = (w << 6) + dtile * 16 + lane16;
        Cb[(size_t)s * D_ + d] = (bf16)oacc[stile][dtile][r];
      }
    }
}

// ------- head sum: out[b,s,d] = sum_n (P0+P1)[b,n,s,d] / (l0+l1)[b,n,s] -------
template<int HS>
__global__ __launch_bounds__(256) void head_sum(const bf16* __restrict__ Part,
                                                const float* __restrict__ Lsum,
                                                float* __restrict__ out) {
  int i = blockIdx.x * 256 + threadIdx.x;
  int m = i >> 5;                      // flattened row 0..8191
  int dc = (i & 31) * 8;               // d-chunk
  int b = m >> 11, s = m & 2047;
  float acc[8] = {};
#pragma unroll
  for (int n = 0; n < NH_; ++n) {
    int g = b * NH_ + n;
    const bf16* p = Part + ((size_t)g * S_ + s) * D_ + dc;
    float lv = Lsum[(size_t)g * S_ + s];
    bf16x8 v0 = *(const bf16x8*)p;
    float a[8];
#pragma unroll
    for (int k = 0; k < 8; ++k) a[k] = (float)v0[k];
    if (HS) {
      lv += Lsum[(size_t)(48 + g) * S_ + s];
      bf16x8 v1 = *(const bf16x8*)(p + (size_t)48 * S_ * D_);
#pragma unroll
      for (int k = 0; k < 8; ++k) a[k] += (float)v1[k];
    }
    float inv = 1.0f / lv;
#pragma unroll
    for (int k = 0; k < 8; ++k) acc[k] += a[k] * inv;
  }
  f32x4 o0, o1;
#pragma unroll
  for (int k = 0; k < 4; ++k) { o0[k] = acc[k]; o1[k] = acc[4 + k]; }
  float* q = out + (size_t)m * D_ + dc;
  *(f32x4*)q = o0;
  *(f32x4*)(q + 4) = o1;
}

extern "C" void kernel_launch(void* const* d_in, const int* in_sizes, int n_in,
                              void* d_out, int out_size, void* d_ws, size_t ws_size,
                              hipStream_t stream) {
  (void)in_sizes; (void)n_in; (void)out_size;
  const float* X    = (const float*)d_in[0];   // fp32 per reference
  const int*   mask = (const int*)d_in[1];
  const float* Wqk  = (const float*)d_in[2];
  const float* bqk  = (const float*)d_in[3];
  const float* Wv   = (const float*)d_in[4];
  const float* bv   = (const float*)d_in[5];
  float* out = (float*)d_out;                  // fp32 per reference output

  char* p = (char*)d_ws;
  bf16*  Xbf  = (bf16*)p;  p += (size_t)M_ * D_ * 2;      // 4.2 MB
  bf16*  Wqkt = (bf16*)p;  p += (size_t)J_ * D_ * 2;      // 1.5 MB
  bf16*  Wvt  = (bf16*)p;  p += (size_t)J_ * D_ * 2;      // 1.5 MB
  bf16*  QKw  = (bf16*)p;  p += (size_t)M_ * J_ * 2;      // 50.3 MB  [m][j]
  bf16*  Vtw  = (bf16*)p;  p += (size_t)J_ * M_ * 2;      // 50.3 MB  [j][m]
  int*   flags= (int*)p;   p += 4096 * 4;                 // 16 KB
  float* Lsum = (float*)p; p += (size_t)2 * 48 * S_ * 4;  // 0.8 MB [h][g][s]
  bf16*  Part = (bf16*)p;                                 // [h][g][s][d]
  size_t need = (size_t)(p - (char*)d_ws) + (size_t)2 * 48 * S_ * D_ * 2; // ~209.5 MB
  int hs = (ws_size >= need) ? 1 : 0;          // fall back to unsplit if ws too small

  prep_k<<<2048 + 384, 256, 0, stream>>>(X, Xbf, Wqk, Wqkt, Wv, Wvt);
  gemm_flags<<<3072 + 4096, 256, 0, stream>>>(Xbf, Wqkt, bqk, QKw, Wvt, bv, Vtw,
                                              mask, flags);
  if (hs) {
    attn_k<1><<<B_ * NH_ * (S_ / 128) * 2, 256, 0, stream>>>(Xbf, QKw, Vtw, mask, flags, Part, Lsum);
    head_sum<1><<<(M_ * D_ / 8) / 256, 256, 0, stream>>>(Part, Lsum, out);
  } else {
    attn_k<0><<<B_ * NH_ * (S_ / 128), 256, 0, stream>>>(Xbf, QKw, Vtw, mask, flags, Part, Lsum);
    head_sum<0><<<(M_ * D_ / 8) / 256, 256, 0, stream>>>(Part, Lsum, out);
  }
}

// Round 9
// 396.943 us; speedup vs baseline: 1.1029x; 1.1029x over previous
//
#include <hip/hip_runtime.h>
#include <stdint.h>

#define B_ 4
#define S_ 2048
#define D_ 256
#define NH_ 12
#define M_ (B_*S_)      // 8192 rows of flattened input
#define J_ (NH_*D_)     // 3072 projection cols
#define LOG2E_ 1.4426950408889634f

typedef __bf16 bf16;
typedef __bf16 bf16x8 __attribute__((ext_vector_type(8)));
typedef __bf16 bf16x4 __attribute__((ext_vector_type(4)));
typedef float  f32x4  __attribute__((ext_vector_type(4)));

#define MFMA16(a,b,c) __builtin_amdgcn_mfma_f32_16x16x32_bf16(a,b,c,0,0,0)

__device__ __forceinline__ void g2lds16(void* l, const void* g) {
  __builtin_amdgcn_global_load_lds(
      (const __attribute__((address_space(1))) unsigned int*)g,
      (__attribute__((address_space(3))) unsigned int*)l, 16, 0, 0);
}

// ---------- prep: X fp32->bf16 (blocks 0..2047) + weight transpose (2048..2431) ----------
__global__ __launch_bounds__(256) void prep_k(const float* __restrict__ X,
                                              bf16* __restrict__ Xbf,
                                              const float* __restrict__ Wqk,
                                              bf16* __restrict__ Wqkt,
                                              const float* __restrict__ Wv,
                                              bf16* __restrict__ Wvt) {
  int bid = blockIdx.x;
  if (bid < 2048) {
    int i = bid * 256 + threadIdx.x;
    f32x4 v = *(const f32x4*)(X + (size_t)i * 4);
    bf16x4 o;
#pragma unroll
    for (int k = 0; k < 4; ++k) o[k] = (bf16)v[k];
    *(bf16x4*)(Xbf + (size_t)i * 4) = o;
  } else {
    int q = bid - 2048;                        // 0..383 = z*192 + y*12 + x
    const float* W = (q >= 192) ? Wv : Wqk;
    bf16* Wt       = (q >= 192) ? Wvt : Wqkt;
    q %= 192;
    int c0 = (q / 12) * 16;
    int j  = (q % 12) * 256 + threadIdx.x;     // coalesced over j
    bf16x8 v0, v1;
#pragma unroll
    for (int i = 0; i < 8; ++i) v0[i] = (bf16)W[(size_t)(c0 + i) * J_ + j];
#pragma unroll
    for (int i = 0; i < 8; ++i) v1[i] = (bf16)W[(size_t)(c0 + 8 + i) * J_ + j];
    *(bf16x8*)(Wt + (size_t)j * D_ + c0)     = v0;
    *(bf16x8*)(Wt + (size_t)j * D_ + c0 + 8) = v1;
  }
}

// ---------------- mask tile flags body: 1 if 64x64 tile is all ones ----------------
__device__ __forceinline__ void mask_flags_body(const int* __restrict__ mask,
                                                int* __restrict__ flags, int bx) {
  int ft = bx & 31, st = (bx >> 5) & 31, b = bx >> 10;
  int t = threadIdx.x;
  const int4* mp4 = (const int4*)(mask + (size_t)b * S_ * S_ +
                                  (size_t)(st * 64 + (t >> 2)) * S_ + ft * 64 + (t & 3) * 16);
  bool ok = true;
#pragma unroll
  for (int i = 0; i < 4; ++i) {
    int4 v = mp4[i];
    ok &= (v.x == 1) & (v.y == 1) & (v.z == 1) & (v.w == 1);
  }
  __shared__ int flag;
  if (t == 0) flag = 1;
  __syncthreads();
  if (!ok) flag = 0;                   // benign race, all write 0
  __syncthreads();
  if (t == 0) flags[bx] = flag;
}

// ---------------- GEMM body: C[M][N] = (A[M][256] * Bm[N][256]^T + bias)*scale --------
// 128x128 tile, BK=64, 4 waves each 64x64. XOR 8-chunk swizzle -> 2-way banks.
// R15: double-buffered LDS + 1-iter prefetch (454->417us total with setprio).
// R18: scale param — QK proj epilogue folds log2e so attn uses bare v_exp_f32.
__device__ __forceinline__ void gemm_body(
    const bf16* __restrict__ A, const bf16* __restrict__ Bm,
    const float* __restrict__ bias, bf16* __restrict__ C,
    int Ndim, int bias_mode, float scale, int bid)
{
  __shared__ bf16 As[2][128 * 64];
  __shared__ bf16 Bs[2][128 * 64];
  const int nbn = Ndim >> 7;
  const int bm = bid / nbn, bn = bid % nbn;
  const int t = threadIdx.x, w = t >> 6, l = t & 63;
  const int lane16 = l & 15, quad = l >> 4;
  const int wm = (w & 1) << 6, wn = (w >> 1) << 6;
  const int srow = t >> 3;
  const int gc = (t & 7) ^ (srow & 7);
  const bf16* Ag = A + (size_t)((bm << 7) + srow) * 256 + gc * 8;
  const bf16* Bg = Bm + (size_t)((bn << 7) + srow) * 256 + gc * 8;

  auto stage = [&](int buf, int k0) {
#pragma unroll
    for (int i = 0; i < 4; ++i)
      g2lds16(&As[buf][(size_t)(i * 256 + (w << 6)) * 8], Ag + (size_t)i * 32 * 256 + k0);
#pragma unroll
    for (int i = 0; i < 4; ++i)
      g2lds16(&Bs[buf][(size_t)(i * 256 + (w << 6)) * 8], Bg + (size_t)i * 32 * 256 + k0);
  };

  f32x4 acc[4][4] = {};
  stage(0, 0);                          // prologue prefetch
  int cur = 0;
  for (int k0 = 0; k0 < 256; k0 += 64) {
    __syncthreads();                    // drains DMA(cur) issued one iter ago
    if (k0 + 64 < 256) stage(cur ^ 1, k0 + 64);  // prefetch under compute
#pragma unroll
    for (int kt = 0; kt < 2; ++kt) {
      bf16x8 af[4], bfr[4];
#pragma unroll
      for (int i = 0; i < 4; ++i)
        af[i] = *(const bf16x8*)(&As[cur][(wm + i * 16 + lane16) * 64 +
                                 (((kt * 4 + quad) ^ (lane16 & 7)) * 8)]);
#pragma unroll
      for (int i = 0; i < 4; ++i)
        bfr[i] = *(const bf16x8*)(&Bs[cur][(wn + i * 16 + lane16) * 64 +
                                  (((kt * 4 + quad) ^ (lane16 & 7)) * 8)]);
#pragma unroll
      for (int i = 0; i < 4; ++i)
#pragma unroll
        for (int jx = 0; jx < 4; ++jx)
          acc[i][jx] = MFMA16(af[i], bfr[jx], acc[i][jx]);
    }
    cur ^= 1;
  }
#pragma unroll
  for (int i = 0; i < 4; ++i)
#pragma unroll
    for (int jx = 0; jx < 4; ++jx) {
      int col = (bn << 7) + wn + jx * 16 + lane16;
#pragma unroll
      for (int r = 0; r < 4; ++r) {
        int row = (bm << 7) + wm + i * 16 + quad * 4 + r;
        float v = (acc[i][jx][r] + (bias_mode ? bias[row] : bias[col])) * scale;
        C[(size_t)row * Ndim + col] = (bf16)v;
      }
    }
}

// R17: both projections + mask_flags in ONE dispatch. blocks [0,1536) QK proj,
// [1536,3072) V^T proj, [3072,7168) mask flags (memory-bound tail, hides).
__global__ __launch_bounds__(256) void gemm_flags(
    const bf16* __restrict__ Xbf, const bf16* __restrict__ Wqkt,
    const float* __restrict__ bqk, bf16* __restrict__ QKw,
    const bf16* __restrict__ Wvt, const float* __restrict__ bv,
    bf16* __restrict__ Vtw,
    const int* __restrict__ mask, int* __restrict__ flags)
{
  int bid = blockIdx.x;
  if (bid < 1536)      gemm_body(Xbf, Wqkt, bqk, QKw, J_, 0, LOG2E_, bid);
  else if (bid < 3072) gemm_body(Wvt, Xbf, bv, Vtw, M_, 1, 1.0f, bid - 1536);
  else                 mask_flags_body(mask, flags, bid - 3072);
}

// ---------------- fused attention ----------------
// XCD-swizzled grid. Block: 4 waves, 128 s-rows; wave owns 32 s-rows for QK.
// TRANSPOSED QK (A=K-frag, B=Q-frag) -> St C-layout col=lane16=s, row=quad*4+r=f.
// K/V double-buffered in LDS, 1-iter prefetch.
// REGISTER CLIFF (R6/R7): 128 VGPR + 128 AGPR = 256/wave = exactly 2
// waves/SIMD. Never add live VGPRs. V STAYS IN LDS (R6: 256->385us).
// NEVER raise launch_bounds min-waves above 2 (r9). NEVER persistent (r12).
// R13 no atomics (331->286). R14 f-split (286->275). R15 setprio (->258).
// R16 PV d-split + raw lgkm mid-barrier (->256).
// R18 LESSONS: exp2f() is PRECISE LIBM -> range-fixup VALU bloat (258->280,
// VALUBusy 25->31). Use __builtin_amdgcn_exp2f (raw v_exp_f32). vfr hoist
// above lgkmcnt(0) SERIALIZES reads into the barrier wait — keep vfr reads
// AFTER the barrier where they overlap other waves' PV.
// R19: prescale kept (QKw *= log2e in GEMM epilogue), exponential via
// __builtin_amdgcn_exp2f; vfr placement = R7.
template<int HS>
__global__ __launch_bounds__(256, 2) void attn_k(
    const bf16* __restrict__ X, const bf16* __restrict__ QK, const bf16* __restrict__ Vt,
    const int* __restrict__ mask, const int* __restrict__ flags,
    bf16* __restrict__ Part, float* __restrict__ Lsum)
{
  __shared__ bf16 Ks[2][32 * 256];
  __shared__ bf16 Vs[2][256 * 32];
  __shared__ bf16 Ps[4][32 * 40];
  // XCD-aware remap: i = xcd + 8*round; round = gh_sub*16 + st; gh = xcd + 8*gh_sub
  const int i  = blockIdx.x;
  const int x  = i & 7, rr = i >> 3;
  const int gh = x + 8 * (rr >> 4);            // HS: 0..95 = half*48 + g ; else 0..47
  const int st = rr & 15;                      // 128-row s-tile
  const int h  = HS ? (gh >= 48 ? 1 : 0) : 0;
  const int g  = gh - 48 * h;                  // 0..47 = b*12+n
  const int b  = g / 12, n = g % 12;
  const int f_beg = h * 1024;
  const int f_end = f_beg + (HS ? 1024 : 2048);
  const int t = threadIdx.x, w = t >> 6, l = t & 63;
  const int lane16 = l & 15, quad = l >> 4;
  const int sw = (st << 7) + (w << 5);          // wave's first of 32 s-rows (QK phase)
  const bf16* Xb = X + (size_t)b * S_ * D_;
  bf16x8 qf[2][8];                              // Q frags (B operand): 2 s-tiles x 256 k
#pragma unroll
  for (int ts = 0; ts < 2; ++ts)
#pragma unroll
    for (int kt = 0; kt < 8; ++kt)
      qf[ts][kt] = *(const bf16x8*)(Xb + (size_t)(sw + ts * 16 + lane16) * D_ + kt * 32 + quad * 8);
  const bf16* QKb = QK + (size_t)b * S_ * J_ + n * D_;
  const bf16* Vtb = Vt + (size_t)n * D_ * M_ + (size_t)b * S_;
  // flags row for this wave's 64-row tile: st*2 + (w>>1); f-index is absolute
  const int* flagb = flags + (b * 32 + st * 2 + (w >> 1)) * 32;
  f32x4 oacc[8][4] = {};                        // O[128s][64d]: [stile][dtile], d-split
  float lsum[2] = {0.f, 0.f};                   // per-lane partial row sums (s=lane16)

  // staging helper: loads f-tile f0 into buffer `buf`
  auto stage = [&](int buf, int f0) {
#pragma unroll
    for (int ii = 0; ii < 4; ++ii) {
      int frow = ii * 8 + (t >> 5);
      int dc = (t & 31) ^ (frow & 7);
      g2lds16(&Ks[buf][ii * 2048 + (w << 9)], QKb + (size_t)(f0 + frow) * J_ + dc * 8);
    }
#pragma unroll
    for (int ii = 0; ii < 4; ++ii) {
      int drow = ii * 64 + (t >> 2);
      int fc = (t & 3) ^ ((drow >> 1) & 3);
      g2lds16(&Vs[buf][ii * 2048 + (w << 9)], Vtb + (size_t)drow * M_ + f0 + fc * 8);
    }
  };

  stage(0, f_beg);                              // prologue prefetch
  int cur = 0;
  for (int f0 = f_beg; f0 < f_end; f0 += 32) {
    __syncthreads();       // drains DMA(cur) (issued a full iter ago); buf cur^1 free
    if (f0 + 32 < f_end) stage(cur ^ 1, f0 + 32);  // prefetch next tile under compute
    // St = K Q^T : C-layout col=lane16=s, row=quad*4+r=f.  A=kf, B=qf.
    f32x4 sfr[2][2] = {};                       // [ts][ct]
    __builtin_amdgcn_s_setprio(1);
#pragma unroll
    for (int kt = 0; kt < 8; ++kt)
#pragma unroll
      for (int ct = 0; ct < 2; ++ct) {
        int fl = ct * 16 + lane16;              // A m-index rows f
        bf16x8 kf = *(const bf16x8*)(&Ks[cur][fl * 256 + (((kt * 4 + quad) ^ (fl & 7)) * 8)]);
        sfr[0][ct] = MFMA16(kf, qf[0][kt], sfr[0][ct]);
        sfr[1][ct] = MFMA16(kf, qf[1][kt], sfr[1][ct]);
      }
    __builtin_amdgcn_s_setprio(0);
    // sfr is pre-scaled by log2e (GEMM epilogue) -> raw v_exp_f32
    float ex[2][2][4];
    if (flagb[f0 >> 6]) {
#pragma unroll
      for (int ts = 0; ts < 2; ++ts)
#pragma unroll
        for (int ct = 0; ct < 2; ++ct)
#pragma unroll
          for (int r = 0; r < 4; ++r)
            ex[ts][ct][r] = __builtin_amdgcn_exp2f(sfr[ts][ct][r]);
    } else {
#pragma unroll
      for (int ts = 0; ts < 2; ++ts)
#pragma unroll
        for (int ct = 0; ct < 2; ++ct)
#pragma unroll
          for (int r = 0; r < 4; ++r) {
            int s = sw + ts * 16 + lane16, f = f0 + ct * 16 + quad * 4 + r;
            float add = (1.0f - (float)mask[(size_t)b * S_ * S_ + (size_t)s * S_ + f])
                        * (-10000.0f * LOG2E_);
            ex[ts][ct][r] = __builtin_amdgcn_exp2f(sfr[ts][ct][r] + add);
          }
    }
#pragma unroll
    for (int ts = 0; ts < 2; ++ts)
      lsum[ts] += ex[ts][0][0] + ex[ts][0][1] + ex[ts][0][2] + ex[ts][0][3]
                + ex[ts][1][0] + ex[ts][1][1] + ex[ts][1][2] + ex[ts][1][3];
    // P -> LDS in A-operand orientation [s=row][f=col], 4 ds_write_b64 per wave
#pragma unroll
    for (int ts = 0; ts < 2; ++ts)
#pragma unroll
      for (int ct = 0; ct < 2; ++ct) {
        int base = (ts * 16 + lane16) * 40 + ct * 16 + quad * 4;
        bf16x4 pv;
        pv[0] = (bf16)ex[ts][ct][0]; pv[1] = (bf16)ex[ts][ct][1];
        pv[2] = (bf16)ex[ts][ct][2]; pv[3] = (bf16)ex[ts][ct][3];
        *(bf16x4*)(&Ps[w][base]) = pv;
      }
    // Ps is BLOCK-shared: publish writes + barrier, but do NOT drain vmcnt —
    // the K/V prefetch DMA must stay in flight.
    asm volatile("s_waitcnt lgkmcnt(0)\n\ts_barrier" ::: "memory");
    // PV d-split: wave owns d in [64w, 64w+64) for ALL 128 block s-rows.
    // vfr reads AFTER the barrier (R18 lesson: hoisting serializes them into
    // the barrier wait; here they overlap other waves' PV).
    bf16x8 vfr[4];
#pragma unroll
    for (int dtile = 0; dtile < 4; ++dtile) {
      int dl = (w << 6) + dtile * 16 + lane16;
      vfr[dtile] = *(const bf16x8*)(&Vs[cur][dl * 32 + ((quad ^ ((dl >> 1) & 3)) * 8)]);
    }
    __builtin_amdgcn_s_setprio(1);
#pragma unroll
    for (int stile = 0; stile < 8; ++stile) {
      bf16x8 pfr = *(const bf16x8*)(&Ps[stile >> 1][(((stile & 1) << 4) + lane16) * 40 + quad * 8]);
#pragma unroll
      for (int dtile = 0; dtile < 4; ++dtile)
        oacc[stile][dtile] = MFMA16(pfr, vfr[dtile], oacc[stile][dtile]);
    }
    __builtin_amdgcn_s_setprio(0);
    cur ^= 1;
  }
  // finalize row sums: reduce across quads (lanes s, s+16, s+32, s+48)
  float tot[2];
#pragma unroll
  for (int ts = 0; ts < 2; ++ts) {
    float rs = lsum[ts];
    rs += __shfl_xor(rs, 16);
    rs += __shfl_xor(rs, 32);
    tot[ts] = rs;                               // every lane: total for s=ts*16+lane16
  }
  // write UN-normalized partial context (bf16) + row sums — exclusive writer
  bf16*  Cb = Part + (size_t)(h * 48 + g) * S_ * D_;
  float* Lb = Lsum + (size_t)(h * 48 + g) * S_;
  if (l < 16) {                                 // quad==0 lanes hold s = ts*16 + l
#pragma unroll
    for (int ts = 0; ts < 2; ++ts) Lb[sw + ts * 16 + l] = tot[ts];
  }
  // O epilogue (d-split layout): s = st*128 + stile*16 + quad*4 + r,
  // d = w*64 + dtile*16 + lane16
#pragma unroll
  for (int stile = 0; stile < 8; ++stile)
#pragma unroll
    for (int r = 0; r < 4; ++r) {
      int s = (st << 7) + stile * 16 + quad * 4 + r;
#pragma unroll
      for (int dtile = 0; dtile < 4; ++dtile) {
        int d = (w << 6) + dtile * 16 + lane16;
        Cb[(size_t)s * D_ + d] = (bf16)oacc[stile][dtile][r];
      }
    }
}

// ------- head sum: out[b,s,d] = sum_n (P0+P1)[b,n,s,d] / (l0+l1)[b,n,s] -------
template<int HS>
__global__ __launch_bounds__(256) void head_sum(const bf16* __restrict__ Part,
                                                const float* __restrict__ Lsum,
                                                float* __restrict__ out) {
  int i = blockIdx.x * 256 + threadIdx.x;
  int m = i >> 5;                      // flattened row 0..8191
  int dc = (i & 31) * 8;               // d-chunk
  int b = m >> 11, s = m & 2047;
  float acc[8] = {};
#pragma unroll
  for (int n = 0; n < NH_; ++n) {
    int g = b * NH_ + n;
    const bf16* p = Part + ((size_t)g * S_ + s) * D_ + dc;
    float lv = Lsum[(size_t)g * S_ + s];
    bf16x8 v0 = *(const bf16x8*)p;
    float a[8];
#pragma unroll
    for (int k = 0; k < 8; ++k) a[k] = (float)v0[k];
    if (HS) {
      lv += Lsum[(size_t)(48 + g) * S_ + s];
      bf16x8 v1 = *(const bf16x8*)(p + (size_t)48 * S_ * D_);
#pragma unroll
      for (int k = 0; k < 8; ++k) a[k] += (float)v1[k];
    }
    float inv = 1.0f / lv;
#pragma unroll
    for (int k = 0; k < 8; ++k) acc[k] += a[k] * inv;
  }
  f32x4 o0, o1;
#pragma unroll
  for (int k = 0; k < 4; ++k) { o0[k] = acc[k]; o1[k] = acc[4 + k]; }
  float* q = out + (size_t)m * D_ + dc;
  *(f32x4*)q = o0;
  *(f32x4*)(q + 4) = o1;
}

extern "C" void kernel_launch(void* const* d_in, const int* in_sizes, int n_in,
                              void* d_out, int out_size, void* d_ws, size_t ws_size,
                              hipStream_t stream) {
  (void)in_sizes; (void)n_in; (void)out_size;
  const float* X    = (const float*)d_in[0];   // fp32 per reference
  const int*   mask = (const int*)d_in[1];
  const float* Wqk  = (const float*)d_in[2];
  const float* bqk  = (const float*)d_in[3];
  const float* Wv   = (const float*)d_in[4];
  const float* bv   = (const float*)d_in[5];
  float* out = (float*)d_out;                  // fp32 per reference output

  char* p = (char*)d_ws;
  bf16*  Xbf  = (bf16*)p;  p += (size_t)M_ * D_ * 2;      // 4.2 MB
  bf16*  Wqkt = (bf16*)p;  p += (size_t)J_ * D_ * 2;      // 1.5 MB
  bf16*  Wvt  = (bf16*)p;  p += (size_t)J_ * D_ * 2;      // 1.5 MB
  bf16*  QKw  = (bf16*)p;  p += (size_t)M_ * J_ * 2;      // 50.3 MB  [m][j]
  bf16*  Vtw  = (bf16*)p;  p += (size_t)J_ * M_ * 2;      // 50.3 MB  [j][m]
  int*   flags= (int*)p;   p += 4096 * 4;                 // 16 KB
  float* Lsum = (float*)p; p += (size_t)2 * 48 * S_ * 4;  // 0.8 MB [h][g][s]
  bf16*  Part = (bf16*)p;                                 // [h][g][s][d]
  size_t need = (size_t)(p - (char*)d_ws) + (size_t)2 * 48 * S_ * D_ * 2; // ~209.5 MB
  int hs = (ws_size >= need) ? 1 : 0;          // fall back to unsplit if ws too small

  prep_k<<<2048 + 384, 256, 0, stream>>>(X, Xbf, Wqk, Wqkt, Wv, Wvt);
  gemm_flags<<<3072 + 4096, 256, 0, stream>>>(Xbf, Wqkt, bqk, QKw, Wvt, bv, Vtw,
                                              mask, flags);
  if (hs) {
    attn_k<1><<<B_ * NH_ * (S_ / 128) * 2, 256, 0, stream>>>(Xbf, QKw, Vtw, mask, flags, Part, Lsum);
    head_sum<1><<<(M_ * D_ / 8) / 256, 256, 0, stream>>>(Part, Lsum, out);
  } else {
    attn_k<0><<<B_ * NH_ * (S_ / 128), 256, 0, stream>>>(Xbf, QKw, Vtw, mask, flags, Part, Lsum);
    head_sum<0><<<(M_ * D_ / 8) / 256, 256, 0, stream>>>(Part, Lsum, out);
  }
}